// Round 5
// baseline (287.144 us; speedup 1.0000x reference)
//
#include <hip/hip_runtime.h>

// TemporalAttention, algebraically folded + MFMA for the two matvec phases.
//   A-phase: QT[B,896] = q[B,288(pad)] @ Mmat[288,896]   (bf16 MFMA, cast fused)
//   B-phase: attention; one workgroup per row, kv staged to LDS via
//            global_load_lds (BW-bound), 4 wave-local online-softmax states
//            merged once through LDS.
//   C-phase: X[B,272] = VT[B,896] @ Pmat[896,272] + bias + residual + LN
// Column layout jj' = h*448 + j (j<444 valid, 444..447 pad, per head h).

namespace {
constexpr int kB = 16384;
constexpr int kN = 20;
constexpr float kScale = 0.08574929257125441f;  // 1/sqrt(136)
constexpr float kLnEps = 1e-5f;

// ws byte offsets
constexpr size_t kOffMsw = 0;                         // ushort[56*9*64*8]
constexpr size_t kOffPsw = kOffMsw + 516096;          // ushort[17*28*64*8]
constexpr size_t kOffQT16 = kOffPsw + 487424;         // ushort[16384*896]
}  // namespace

typedef __attribute__((ext_vector_type(8))) short s8v;
typedef __attribute__((ext_vector_type(4))) float f4v;

__device__ __forceinline__ unsigned short f2bf(float x) {
  unsigned int u = __float_as_uint(x);
  unsigned int r = (u + 0x7FFFu + ((u >> 16) & 1u)) >> 16;
  return (unsigned short)r;
}
__device__ __forceinline__ float bf2f(unsigned short h) {
  return __uint_as_float(((unsigned int)h) << 16);
}
__device__ __forceinline__ float fma4(float4 a, float4 b, float acc) {
  acc = fmaf(a.x, b.x, acc);
  acc = fmaf(a.y, b.y, acc);
  acc = fmaf(a.z, b.z, acc);
  acc = fmaf(a.w, b.w, acc);
  return acc;
}
// async global->LDS, 16B per lane; lds dest must be wave-uniform base (+lane*16 by HW)
__device__ __forceinline__ void gload16(const float4* g, float4* l) {
  __builtin_amdgcn_global_load_lds(
      (const __attribute__((address_space(1))) void*)g,
      (__attribute__((address_space(3))) void*)l, 16, 0, 0);
}

// Msw[tile 0..55][ks 0..8][lane][e 0..7]: B-frag order for GEMM-A.
// Block = (tile, ks, e); lane computes one element's 136-dot.
__global__ __launch_bounds__(64) void k_build_msw(const float* __restrict__ WQ,
                                                  const float* __restrict__ WK,
                                                  unsigned short* __restrict__ Msw) {
  const int e = blockIdx.x % 8;
  const int ks = (blockIdx.x / 8) % 9;
  const int tile = blockIdx.x / 72;
  const int l = threadIdx.x;
  const int jj = tile * 16 + (l & 15);
  const int h = jj / 448;
  const int j = jj - h * 448;
  const int i = ks * 32 + (l >> 4) * 8 + e;
  float s = 0.f;
  if (j < 444 && i < 272) {
    const float* wq = WQ + h * 136 * 272 + i;
    const float* wk = WK + h * 136 * 444 + j;
#pragma unroll 8
    for (int d = 0; d < 136; ++d) s = fmaf(wq[d * 272], wk[d * 444], s);
  }
  Msw[((size_t)(tile * 9 + ks) * 64 + l) * 8 + e] = f2bf(s);
}

// Psw[tile 0..16][ks 0..27][lane][e]: B-frag order for GEMM-C.
// Pmat[k][n] = sum_d WO[n][h*136+d] * WV[h*136+d][j]; WO rows contiguous in d.
__global__ __launch_bounds__(64) void k_build_psw(const float* __restrict__ WO,
                                                  const float* __restrict__ WV,
                                                  unsigned short* __restrict__ Psw) {
  const int e = blockIdx.x % 8;
  const int ks = (blockIdx.x / 8) % 28;
  const int tile = blockIdx.x / 224;
  const int l = threadIdx.x;
  const int n = tile * 16 + (l & 15);
  const int k = ks * 32 + (l >> 4) * 8 + e;
  const int h = k / 448;
  const int j = k - h * 448;
  float s = 0.f;
  if (j < 444) {
    const float* wo = WO + (size_t)n * 272 + h * 136;
    const float* wv = WV + h * 136 * 444 + j;
#pragma unroll 8
    for (int d = 0; d < 136; ++d) s = fmaf(wo[d], wv[d * 444], s);
  }
  Psw[((size_t)(tile * 28 + ks) * 64 + l) * 8 + e] = f2bf(s);
}

// GEMM-A (cast fused): QT16[16 rows/block][896] = bf16(q) @ Mmat.
__global__ __launch_bounds__(256) void k_gemm_a(const float* __restrict__ node,
                                                const float* __restrict__ timef,
                                                const unsigned short* __restrict__ Msw,
                                                unsigned short* __restrict__ QT16) {
  const int tid = threadIdx.x;
  const int l = tid & 63, w = tid >> 6;
  const int m0 = blockIdx.x * 16;
  const int mrow = m0 + (l & 15);
  const int koff = (l >> 4) * 8;
  const float4* n4 = reinterpret_cast<const float4*>(node + (size_t)mrow * 172);
  const float4* t4 = reinterpret_cast<const float4*>(timef + (size_t)mrow * 100);
  const float4 z4 = make_float4(0.f, 0.f, 0.f, 0.f);
  f4v acc[14];
#pragma unroll
  for (int t = 0; t < 14; ++t) acc[t] = (f4v){0.f, 0.f, 0.f, 0.f};
  for (int ks = 0; ks < 9; ++ks) {
    const int c0 = ks * 32 + koff;
    float4 lo = z4, hi = z4;
    if (c0 + 8 <= 172) {
      lo = n4[c0 / 4];
      hi = n4[c0 / 4 + 1];
    } else if (c0 == 168) {
      lo = n4[42];
      hi = t4[0];
    } else if (c0 + 8 <= 272) {
      lo = t4[(c0 - 172) / 4];
      hi = t4[(c0 - 172) / 4 + 1];
    }
    s8v a;
    a[0] = (short)f2bf(lo.x); a[1] = (short)f2bf(lo.y);
    a[2] = (short)f2bf(lo.z); a[3] = (short)f2bf(lo.w);
    a[4] = (short)f2bf(hi.x); a[5] = (short)f2bf(hi.y);
    a[6] = (short)f2bf(hi.z); a[7] = (short)f2bf(hi.w);
    const unsigned short* bp = Msw + ((size_t)(w * 14) * 9 + ks) * 64 * 8 + (size_t)l * 8;
#pragma unroll
    for (int t = 0; t < 14; ++t) {
      const s8v b = *reinterpret_cast<const s8v*>(bp + (size_t)t * 9 * 64 * 8);
      acc[t] = __builtin_amdgcn_mfma_f32_16x16x32_bf16(a, b, acc[t], 0, 0, 0);
    }
  }
  const int r0 = (l >> 4) * 4;
#pragma unroll
  for (int t = 0; t < 14; ++t) {
    const int n = (w * 14 + t) * 16 + (l & 15);
#pragma unroll
    for (int r = 0; r < 4; ++r)
      QT16[(size_t)(m0 + r0 + r) * 896 + n] = f2bf(acc[t][r]);
  }
}

// Phase B: one workgroup (256 thr) per batch row. kv (20x444 f32 = 35.5 KB)
// staged to LDS via global_load_lds. Wave w owns neighbors 5w..5w+4; lane l
// holds float4 slots l and 64+l (l<47). Wave-local online softmax; 4 states
// merged via LDS; vbuf for merge reuses the kv buffer.
__global__ __launch_bounds__(256) void k_attn(const float* __restrict__ nnode,
                                              const float* __restrict__ nedge,
                                              const float* __restrict__ ntime,
                                              const int* __restrict__ mask,
                                              unsigned short* __restrict__ QT16) {
  __shared__ float4 kvbuf[2220];   // 35520 B; also reused as vbuf[2][4][111]
  __shared__ float mrg[4][4];
  const int t = threadIdx.x;
  const int l = t & 63, w = t >> 6;
  const int b = blockIdx.x;
  const bool v1 = (l < 47);
  const float4 z4 = make_float4(0.f, 0.f, 0.f, 0.f);
  const float4* nn = reinterpret_cast<const float4*>(nnode) + (size_t)b * kN * 43;
  const float4* ne = reinterpret_cast<const float4*>(nedge) + (size_t)b * kN * 43;
  const float4* nt = reinterpret_cast<const float4*>(ntime) + (size_t)b * kN * 25;

  // stage all 2220 float4 slots: slot s -> neighbor n=s/111, piece j4=s%111
#pragma unroll
  for (int r = 0; r < 9; ++r) {
    const int s = t + 256 * r;
    if (r < 8 || s < 2220) {
      const int n = s / 111;
      const int j4 = s - n * 111;
      const float4* src = (j4 < 43) ? nn + n * 43 + j4
                        : (j4 < 86) ? ne + n * 43 + (j4 - 43)
                                    : nt + n * 25 + (j4 - 86);
      gload16(src, &kvbuf[w * 64 + 256 * r]);  // lds base wave-uniform
    }
  }

  // q~ for this row (issued before the drain; they complete with it)
  unsigned short* qrow = QT16 + (size_t)b * 896;
  auto ldq = [&](int so) {
    const ushort4 u = *reinterpret_cast<const ushort4*>(qrow + so);
    return make_float4(bf2f(u.x), bf2f(u.y), bf2f(u.z), bf2f(u.w));
  };
  const float4 q00 = ldq(4 * l);
  const float4 q01 = v1 ? ldq(256 + 4 * l) : z4;
  const float4 q10 = ldq(448 + 4 * l);
  const float4 q11 = v1 ? ldq(448 + 256 + 4 * l) : z4;
  int mk[5];
#pragma unroll
  for (int it = 0; it < 5; ++it) mk[it] = mask[(size_t)b * kN + w * 5 + it];

  asm volatile("s_waitcnt vmcnt(0)" ::: "memory");
  __syncthreads();

  float4 va00 = z4, va01 = z4, va10 = z4, va11 = z4;
  float m0 = -1e30f, m1 = -1e30f, l0 = 0.f, l1 = 0.f;
#pragma unroll
  for (int it = 0; it < 5; ++it) {
    const int n = w * 5 + it;
    const float4 kv0 = kvbuf[n * 111 + l];
    const float4 kv1 = v1 ? kvbuf[n * 111 + 64 + l] : z4;
    float ps0 = fma4(q01, kv1, fma4(q00, kv0, 0.f));
    float ps1 = fma4(q11, kv1, fma4(q10, kv0, 0.f));
#pragma unroll
    for (int off = 32; off >= 1; off >>= 1) {
      ps0 += __shfl_xor(ps0, off, 64);
      ps1 += __shfl_xor(ps1, off, 64);
    }
    const bool msk = (mk[it] == 0);
    const float sc0 = msk ? -1e10f : ps0 * kScale;
    const float sc1 = msk ? -1e10f : ps1 * kScale;
    const float mn0 = fmaxf(m0, sc0);
    const float al0 = __expf(m0 - mn0);
    const float pp0 = __expf(sc0 - mn0);
    m0 = mn0;
    l0 = fmaf(l0, al0, pp0);
    const float mn1 = fmaxf(m1, sc1);
    const float al1 = __expf(m1 - mn1);
    const float pp1 = __expf(sc1 - mn1);
    m1 = mn1;
    l1 = fmaf(l1, al1, pp1);
    va00.x = fmaf(pp0, kv0.x, va00.x * al0);
    va00.y = fmaf(pp0, kv0.y, va00.y * al0);
    va00.z = fmaf(pp0, kv0.z, va00.z * al0);
    va00.w = fmaf(pp0, kv0.w, va00.w * al0);
    va01.x = fmaf(pp0, kv1.x, va01.x * al0);
    va01.y = fmaf(pp0, kv1.y, va01.y * al0);
    va01.z = fmaf(pp0, kv1.z, va01.z * al0);
    va01.w = fmaf(pp0, kv1.w, va01.w * al0);
    va10.x = fmaf(pp1, kv0.x, va10.x * al1);
    va10.y = fmaf(pp1, kv0.y, va10.y * al1);
    va10.z = fmaf(pp1, kv0.z, va10.z * al1);
    va10.w = fmaf(pp1, kv0.w, va10.w * al1);
    va11.x = fmaf(pp1, kv1.x, va11.x * al1);
    va11.y = fmaf(pp1, kv1.y, va11.y * al1);
    va11.z = fmaf(pp1, kv1.z, va11.z * al1);
    va11.w = fmaf(pp1, kv1.w, va11.w * al1);
  }

  if (l == 0) {
    mrg[w][0] = m0; mrg[w][1] = l0; mrg[w][2] = m1; mrg[w][3] = l1;
  }
  __syncthreads();  // all kv reads done; kvbuf reusable as vbuf
  const float M0 = fmaxf(fmaxf(mrg[0][0], mrg[1][0]), fmaxf(mrg[2][0], mrg[3][0]));
  const float M1 = fmaxf(fmaxf(mrg[0][2], mrg[1][2]), fmaxf(mrg[2][2], mrg[3][2]));
  const float L0 = mrg[0][1] * __expf(mrg[0][0] - M0) + mrg[1][1] * __expf(mrg[1][0] - M0) +
                   mrg[2][1] * __expf(mrg[2][0] - M0) + mrg[3][1] * __expf(mrg[3][0] - M0);
  const float L1 = mrg[0][3] * __expf(mrg[0][2] - M1) + mrg[1][3] * __expf(mrg[1][2] - M1) +
                   mrg[2][3] * __expf(mrg[2][2] - M1) + mrg[3][3] * __expf(mrg[3][2] - M1);
  const float c0 = __expf(m0 - M0);
  const float c1 = __expf(m1 - M1);
  float4* vbuf = kvbuf;  // [h][w][slot] = [(h*4+w)*111 + slot]
  {
    float4 a = va00, bq = va01, c = va10, d = va11;
    a.x *= c0; a.y *= c0; a.z *= c0; a.w *= c0;
    bq.x *= c0; bq.y *= c0; bq.z *= c0; bq.w *= c0;
    c.x *= c1; c.y *= c1; c.z *= c1; c.w *= c1;
    d.x *= c1; d.y *= c1; d.z *= c1; d.w *= c1;
    vbuf[(0 * 4 + w) * 111 + l] = a;
    if (v1) vbuf[(0 * 4 + w) * 111 + 64 + l] = bq;
    vbuf[(1 * 4 + w) * 111 + l] = c;
    if (v1) vbuf[(1 * 4 + w) * 111 + 64 + l] = d;
  }
  __syncthreads();
  // final: thread t<111 -> head0 slot t; 128<=t<239 -> head1 slot t-128
  int h = -1, s = 0;
  if (t < 111) { h = 0; s = t; }
  else if (t >= 128 && t < 239) { h = 1; s = t - 128; }
  if (h >= 0) {
    const float4 s0 = vbuf[(h * 4 + 0) * 111 + s];
    const float4 s1 = vbuf[(h * 4 + 1) * 111 + s];
    const float4 s2 = vbuf[(h * 4 + 2) * 111 + s];
    const float4 s3 = vbuf[(h * 4 + 3) * 111 + s];
    const float inv = 1.0f / ((h == 0) ? L0 : L1);
    ushort4 u;
    u.x = f2bf((s0.x + s1.x + s2.x + s3.x) * inv);
    u.y = f2bf((s0.y + s1.y + s2.y + s3.y) * inv);
    u.z = f2bf((s0.z + s1.z + s2.z + s3.z) * inv);
    u.w = f2bf((s0.w + s1.w + s2.w + s3.w) * inv);
    *reinterpret_cast<ushort4*>(qrow + h * 448 + 4 * s) = u;
  }
}

// GEMM-C + bias + residual + LayerNorm. 4 waves; wave w owns n-tiles w,w+4,...
__global__ __launch_bounds__(256) void k_out_mfma(const unsigned short* __restrict__ VT16,
                                                  const unsigned short* __restrict__ Psw,
                                                  const float* __restrict__ node,
                                                  const float* __restrict__ timef,
                                                  const float* __restrict__ bO,
                                                  const float* __restrict__ g,
                                                  const float* __restrict__ be,
                                                  float* __restrict__ out) {
  __shared__ float xl[16][273];
  const int tid = threadIdx.x;
  const int l = tid & 63, w = tid >> 6;
  const int m0 = blockIdx.x * 16;
  const int mrow = m0 + (l & 15);
  const int koff = (l >> 4) * 8;
  f4v acc[5];
#pragma unroll
  for (int i = 0; i < 5; ++i) acc[i] = (f4v){0.f, 0.f, 0.f, 0.f};
  for (int ks = 0; ks < 28; ++ks) {
    const s8v a = *reinterpret_cast<const s8v*>(VT16 + (size_t)mrow * 896 + ks * 32 + koff);
#pragma unroll
    for (int i = 0; i < 5; ++i) {
      const int t = w + 4 * i;
      if (t < 17) {
        const s8v bfr = *reinterpret_cast<const s8v*>(Psw + ((size_t)(t * 28 + ks) * 64 + l) * 8);
        acc[i] = __builtin_amdgcn_mfma_f32_16x16x32_bf16(a, bfr, acc[i], 0, 0, 0);
      }
    }
  }
  const int r0 = (l >> 4) * 4;
#pragma unroll
  for (int i = 0; i < 5; ++i) {
    const int t = w + 4 * i;
    if (t < 17) {
#pragma unroll
      for (int r = 0; r < 4; ++r) xl[r0 + r][t * 16 + (l & 15)] = acc[i][r];
    }
  }
  __syncthreads();
  for (int bb = w; bb < 16; bb += 4) {
    const int b = m0 + bb;
    float v[5];
    float sum = 0.f, sq = 0.f;
#pragma unroll
    for (int k = 0; k < 5; ++k) {
      const int o = l + 64 * k;
      v[k] = 0.f;
      if (o < 272) {
        const float r = (o < 172) ? node[(size_t)b * 172 + o] : timef[(size_t)b * 100 + (o - 172)];
        const float x = xl[bb][o] + bO[o] + r;
        v[k] = x;
        sum += x;
        sq = fmaf(x, x, sq);
      }
    }
#pragma unroll
    for (int off = 32; off >= 1; off >>= 1) {
      sum += __shfl_xor(sum, off, 64);
      sq += __shfl_xor(sq, off, 64);
    }
    const float mu = sum * (1.0f / 272.0f);
    const float var = sq * (1.0f / 272.0f) - mu * mu;
    const float rs = rsqrtf(var + kLnEps);
#pragma unroll
    for (int k = 0; k < 5; ++k) {
      const int o = l + 64 * k;
      if (o < 272) out[(size_t)b * 272 + o] = (v[k] - mu) * rs * g[o] + be[o];
    }
  }
}

extern "C" void kernel_launch(void* const* d_in, const int* in_sizes, int n_in,
                              void* d_out, int out_size, void* d_ws, size_t ws_size,
                              hipStream_t stream) {
  const float* node = (const float*)d_in[0];
  const float* timef = (const float*)d_in[1];
  const float* nnode = (const float*)d_in[2];
  const float* ntime = (const float*)d_in[3];
  const float* nedge = (const float*)d_in[4];
  const int* mask = (const int*)d_in[5];
  const float* WQ = (const float*)d_in[6];
  const float* WK = (const float*)d_in[7];
  const float* WV = (const float*)d_in[8];
  const float* WO = (const float*)d_in[9];
  const float* bO = (const float*)d_in[10];
  const float* g = (const float*)d_in[11];
  const float* be = (const float*)d_in[12];

  char* ws = (char*)d_ws;
  unsigned short* Msw = (unsigned short*)(ws + kOffMsw);
  unsigned short* Psw = (unsigned short*)(ws + kOffPsw);
  unsigned short* QT16 = (unsigned short*)(ws + kOffQT16);
  float* out = (float*)d_out;

  hipLaunchKernelGGL(k_build_msw, dim3(56 * 9 * 8), dim3(64), 0, stream, WQ, WK, Msw);
  hipLaunchKernelGGL(k_build_psw, dim3(17 * 28 * 8), dim3(64), 0, stream, WO, WV, Psw);
  hipLaunchKernelGGL(k_gemm_a, dim3(kB / 16), dim3(256), 0, stream, node, timef, Msw, QT16);
  hipLaunchKernelGGL(k_attn, dim3(kB), dim3(256), 0, stream, nnode, nedge, ntime, mask, QT16);
  hipLaunchKernelGGL(k_out_mfma, dim3(kB / 16), dim3(256), 0, stream, QT16, Psw, node, timef, bO, g, be, out);
}

// Round 7
// 269.262 us; speedup vs baseline: 1.0664x; 1.0664x over previous
//
#include <hip/hip_runtime.h>

// TemporalAttention, algebraically folded + MFMA for the two matvec phases.
//   A-phase: QT[B,896] = q[B,288(pad)] @ Mmat[288,896]   (bf16 MFMA, cast fused)
//   B-phase: attention; wave = 1 row, all kv in registers (read once),
//            DPP dot-reduce; softmax on wave-uniform scalars (no LDS/DS ops).
//   C-phase: X[B,272] = VT[B,896] @ Pmat[896,272] + bias + residual + LN
// Column layout jj' = h*448 + j (j<444 valid, 444..447 pad, per head h).

namespace {
constexpr int kB = 16384;
constexpr int kN = 20;
constexpr float kScale = 0.08574929257125441f;  // 1/sqrt(136)
constexpr float kLnEps = 1e-5f;

// ws byte offsets
constexpr size_t kOffMsw = 0;                         // ushort[56*9*64*8]
constexpr size_t kOffPsw = kOffMsw + 516096;          // ushort[17*28*64*8]
constexpr size_t kOffQT16 = kOffPsw + 487424;         // ushort[16384*896]
}  // namespace

typedef __attribute__((ext_vector_type(8))) short s8v;
typedef __attribute__((ext_vector_type(4))) float f4v;

__device__ __forceinline__ unsigned short f2bf(float x) {
  unsigned int u = __float_as_uint(x);
  unsigned int r = (u + 0x7FFFu + ((u >> 16) & 1u)) >> 16;
  return (unsigned short)r;
}
__device__ __forceinline__ float bf2f(unsigned short h) {
  return __uint_as_float(((unsigned int)h) << 16);
}
__device__ __forceinline__ float fma4(float4 a, float4 b, float acc) {
  acc = fmaf(a.x, b.x, acc);
  acc = fmaf(a.y, b.y, acc);
  acc = fmaf(a.z, b.z, acc);
  acc = fmaf(a.w, b.w, acc);
  return acc;
}

// ---- DPP wave64 sum (VALU only; full sum lands in lane 63) ----
__device__ __forceinline__ float dpp_sum(float x) {
  int v = __float_as_int(x), t;
  t = __builtin_amdgcn_update_dpp(0, v, 0x111, 0xf, 0xf, true);  // row_shr:1
  v = __float_as_int(__int_as_float(v) + __int_as_float(t));
  t = __builtin_amdgcn_update_dpp(0, v, 0x112, 0xf, 0xf, true);  // row_shr:2
  v = __float_as_int(__int_as_float(v) + __int_as_float(t));
  t = __builtin_amdgcn_update_dpp(0, v, 0x114, 0xf, 0xf, true);  // row_shr:4
  v = __float_as_int(__int_as_float(v) + __int_as_float(t));
  t = __builtin_amdgcn_update_dpp(0, v, 0x118, 0xf, 0xf, true);  // row_shr:8
  v = __float_as_int(__int_as_float(v) + __int_as_float(t));
  t = __builtin_amdgcn_update_dpp(0, v, 0x142, 0xf, 0xf, true);  // row_bcast:15
  v = __float_as_int(__int_as_float(v) + __int_as_float(t));
  t = __builtin_amdgcn_update_dpp(0, v, 0x143, 0xf, 0xf, true);  // row_bcast:31
  v = __float_as_int(__int_as_float(v) + __int_as_float(t));
  return __int_as_float(v);
}
__device__ __forceinline__ float rdl63(float x) {
  return __int_as_float(__builtin_amdgcn_readlane(__float_as_int(x), 63));
}
__device__ __forceinline__ float rfl(float x) {
  return __int_as_float(__builtin_amdgcn_readfirstlane(__float_as_int(x)));
}

// Msw[tile 0..55][ks 0..8][lane][e 0..7]: B-frag order for GEMM-A.
__global__ __launch_bounds__(64) void k_build_msw(const float* __restrict__ WQ,
                                                  const float* __restrict__ WK,
                                                  unsigned short* __restrict__ Msw) {
  const int e = blockIdx.x % 8;
  const int ks = (blockIdx.x / 8) % 9;
  const int tile = blockIdx.x / 72;
  const int l = threadIdx.x;
  const int jj = tile * 16 + (l & 15);
  const int h = jj / 448;
  const int j = jj - h * 448;
  const int i = ks * 32 + (l >> 4) * 8 + e;
  float s = 0.f;
  if (j < 444 && i < 272) {
    const float* wq = WQ + h * 136 * 272 + i;
    const float* wk = WK + h * 136 * 444 + j;
#pragma unroll 8
    for (int d = 0; d < 136; ++d) s = fmaf(wq[d * 272], wk[d * 444], s);
  }
  Msw[((size_t)(tile * 9 + ks) * 64 + l) * 8 + e] = f2bf(s);
}

// Psw[tile 0..16][ks 0..27][lane][e]: B-frag order for GEMM-C.
__global__ __launch_bounds__(64) void k_build_psw(const float* __restrict__ WO,
                                                  const float* __restrict__ WV,
                                                  unsigned short* __restrict__ Psw) {
  const int e = blockIdx.x % 8;
  const int ks = (blockIdx.x / 8) % 28;
  const int tile = blockIdx.x / 224;
  const int l = threadIdx.x;
  const int n = tile * 16 + (l & 15);
  const int k = ks * 32 + (l >> 4) * 8 + e;
  const int h = k / 448;
  const int j = k - h * 448;
  float s = 0.f;
  if (j < 444) {
    const float* wo = WO + (size_t)n * 272 + h * 136;
    const float* wv = WV + h * 136 * 444 + j;
#pragma unroll 8
    for (int d = 0; d < 136; ++d) s = fmaf(wo[d], wv[d * 444], s);
  }
  Psw[((size_t)(tile * 28 + ks) * 64 + l) * 8 + e] = f2bf(s);
}

// GEMM-A (cast fused): QT16[16 rows/block][896] = bf16(q) @ Mmat.
__global__ __launch_bounds__(256) void k_gemm_a(const float* __restrict__ node,
                                                const float* __restrict__ timef,
                                                const unsigned short* __restrict__ Msw,
                                                unsigned short* __restrict__ QT16) {
  const int tid = threadIdx.x;
  const int l = tid & 63, w = tid >> 6;
  const int m0 = blockIdx.x * 16;
  const int mrow = m0 + (l & 15);
  const int koff = (l >> 4) * 8;
  const float4* n4 = reinterpret_cast<const float4*>(node + (size_t)mrow * 172);
  const float4* t4 = reinterpret_cast<const float4*>(timef + (size_t)mrow * 100);
  const float4 z4 = make_float4(0.f, 0.f, 0.f, 0.f);
  f4v acc[14];
#pragma unroll
  for (int t = 0; t < 14; ++t) acc[t] = (f4v){0.f, 0.f, 0.f, 0.f};
  for (int ks = 0; ks < 9; ++ks) {
    const int c0 = ks * 32 + koff;
    float4 lo = z4, hi = z4;
    if (c0 + 8 <= 172) {
      lo = n4[c0 / 4];
      hi = n4[c0 / 4 + 1];
    } else if (c0 == 168) {
      lo = n4[42];
      hi = t4[0];
    } else if (c0 + 8 <= 272) {
      lo = t4[(c0 - 172) / 4];
      hi = t4[(c0 - 172) / 4 + 1];
    }
    s8v a;
    a[0] = (short)f2bf(lo.x); a[1] = (short)f2bf(lo.y);
    a[2] = (short)f2bf(lo.z); a[3] = (short)f2bf(lo.w);
    a[4] = (short)f2bf(hi.x); a[5] = (short)f2bf(hi.y);
    a[6] = (short)f2bf(hi.z); a[7] = (short)f2bf(hi.w);
    const unsigned short* bp = Msw + ((size_t)(w * 14) * 9 + ks) * 64 * 8 + (size_t)l * 8;
#pragma unroll
    for (int t = 0; t < 14; ++t) {
      const s8v b = *reinterpret_cast<const s8v*>(bp + (size_t)t * 9 * 64 * 8);
      acc[t] = __builtin_amdgcn_mfma_f32_16x16x32_bf16(a, b, acc[t], 0, 0, 0);
    }
  }
  const int r0 = (l >> 4) * 4;
#pragma unroll
  for (int t = 0; t < 14; ++t) {
    const int n = (w * 14 + t) * 16 + (l & 15);
#pragma unroll
    for (int r = 0; r < 4; ++r)
      QT16[(size_t)(m0 + r0 + r) * 896 + n] = f2bf(acc[t][r]);
  }
}

// Phase B: wave = 1 row. kv (20 x 111 float4) entirely in registers, read once.
// Lane l holds float4 slots l and 64+l (l<47). Per-neighbor dot -> DPP sum ->
// readlane(63) gives a wave-uniform score; softmax done on uniform scalars
// (p stashed to SGPR via readfirstlane); pass 2 re-multiplies register kv.
__global__ __launch_bounds__(256, 2) void k_attn(const float* __restrict__ nnode,
                                                 const float* __restrict__ nedge,
                                                 const float* __restrict__ ntime,
                                                 const int* __restrict__ mask,
                                                 unsigned short* __restrict__ QT16) {
  const int l = threadIdx.x & 63;
  const int w = threadIdx.x >> 6;
  const int b = blockIdx.x * 4 + w;
  const bool v1 = (l < 47);
  const float4 z4 = make_float4(0.f, 0.f, 0.f, 0.f);
  const float4* nn = reinterpret_cast<const float4*>(nnode) + (size_t)b * kN * 43;
  const float4* ne = reinterpret_cast<const float4*>(nedge) + (size_t)b * kN * 43;
  const float4* nt = reinterpret_cast<const float4*>(ntime) + (size_t)b * kN * 25;

  // ---- load all kv into registers (the only global read of neighbor data)
  float4 kv0[kN], kv1[kN];
#pragma unroll
  for (int n = 0; n < kN; ++n) {
    kv0[n] = (l < 43) ? nn[n * 43 + l] : ne[n * 43 + (l - 43)];
    kv1[n] = z4;
    if (v1) {
      const int j4 = 64 + l;
      kv1[n] = (j4 < 86) ? ne[n * 43 + (j4 - 43)] : nt[n * 25 + (j4 - 86)];
    }
  }

  // ---- q~ (bf16 -> f32)
  unsigned short* qrow = QT16 + (size_t)b * 896;
  auto ldq = [&](int so) {
    const ushort4 u = *reinterpret_cast<const ushort4*>(qrow + so);
    return make_float4(bf2f(u.x), bf2f(u.y), bf2f(u.z), bf2f(u.w));
  };
  const float4 q00 = ldq(4 * l);
  const float4 q01 = v1 ? ldq(256 + 4 * l) : z4;
  const float4 q10 = ldq(448 + 4 * l);
  const float4 q11 = v1 ? ldq(448 + 256 + 4 * l) : z4;
  const int* mrow = mask + (size_t)b * kN;

  // ---- pass 1: per-neighbor dots -> uniform scores (SGPR)
  float s0[kN], s1[kN];
#pragma unroll
  for (int n = 0; n < kN; ++n) {
    float ps0 = fma4(q01, kv1[n], fma4(q00, kv0[n], 0.f));
    float ps1 = fma4(q11, kv1[n], fma4(q10, kv0[n], 0.f));
    s0[n] = rdl63(dpp_sum(ps0));
    s1[n] = rdl63(dpp_sum(ps1));
  }

  // ---- softmax on uniform scalars (matches jnp: -1e10 fill, max-sub)
  float M0 = -1e30f, M1 = -1e30f;
#pragma unroll
  for (int n = 0; n < kN; ++n) {
    const bool mz = (mrow[n] == 0);
    s0[n] = mz ? -1e10f : s0[n] * kScale;
    s1[n] = mz ? -1e10f : s1[n] * kScale;
    M0 = fmaxf(M0, s0[n]);
    M1 = fmaxf(M1, s1[n]);
  }
  float L0 = 0.f, L1 = 0.f;
  float p0[kN], p1[kN];
#pragma unroll
  for (int n = 0; n < kN; ++n) {
    p0[n] = rfl(__expf(s0[n] - M0));
    p1[n] = rfl(__expf(s1[n] - M1));
    L0 += p0[n];
    L1 += p1[n];
  }
  const float i0 = rfl(1.0f / L0);
  const float i1 = rfl(1.0f / L1);

  // ---- pass 2: PV from register kv with uniform weights
  float4 va00 = z4, va01 = z4, va10 = z4, va11 = z4;
#pragma unroll
  for (int n = 0; n < kN; ++n) {
    const float sp0 = p0[n] * i0;
    const float sp1 = p1[n] * i1;
    va00.x = fmaf(sp0, kv0[n].x, va00.x);
    va00.y = fmaf(sp0, kv0[n].y, va00.y);
    va00.z = fmaf(sp0, kv0[n].z, va00.z);
    va00.w = fmaf(sp0, kv0[n].w, va00.w);
    va01.x = fmaf(sp0, kv1[n].x, va01.x);
    va01.y = fmaf(sp0, kv1[n].y, va01.y);
    va01.z = fmaf(sp0, kv1[n].z, va01.z);
    va01.w = fmaf(sp0, kv1[n].w, va01.w);
    va10.x = fmaf(sp1, kv0[n].x, va10.x);
    va10.y = fmaf(sp1, kv0[n].y, va10.y);
    va10.z = fmaf(sp1, kv0[n].z, va10.z);
    va10.w = fmaf(sp1, kv0[n].w, va10.w);
    va11.x = fmaf(sp1, kv1[n].x, va11.x);
    va11.y = fmaf(sp1, kv1[n].y, va11.y);
    va11.z = fmaf(sp1, kv1[n].z, va11.z);
    va11.w = fmaf(sp1, kv1[n].w, va11.w);
  }

  auto stq = [&](int so, float4 v) {
    ushort4 u;
    u.x = f2bf(v.x); u.y = f2bf(v.y); u.z = f2bf(v.z); u.w = f2bf(v.w);
    *reinterpret_cast<ushort4*>(qrow + so) = u;
  };
  stq(4 * l, va00);
  if (v1) stq(256 + 4 * l, va01);
  stq(448 + 4 * l, va10);
  if (v1) stq(448 + 256 + 4 * l, va11);
}

// GEMM-C + bias + residual + LayerNorm. 4 waves; wave w owns n-tiles w,w+4,...
__global__ __launch_bounds__(256) void k_out_mfma(const unsigned short* __restrict__ VT16,
                                                  const unsigned short* __restrict__ Psw,
                                                  const float* __restrict__ node,
                                                  const float* __restrict__ timef,
                                                  const float* __restrict__ bO,
                                                  const float* __restrict__ g,
                                                  const float* __restrict__ be,
                                                  float* __restrict__ out) {
  __shared__ float xl[16][273];
  const int tid = threadIdx.x;
  const int l = tid & 63, w = tid >> 6;
  const int m0 = blockIdx.x * 16;
  const int mrow = m0 + (l & 15);
  const int koff = (l >> 4) * 8;
  f4v acc[5];
#pragma unroll
  for (int i = 0; i < 5; ++i) acc[i] = (f4v){0.f, 0.f, 0.f, 0.f};
  for (int ks = 0; ks < 28; ++ks) {
    const s8v a = *reinterpret_cast<const s8v*>(VT16 + (size_t)mrow * 896 + ks * 32 + koff);
#pragma unroll
    for (int i = 0; i < 5; ++i) {
      const int t = w + 4 * i;
      if (t < 17) {
        const s8v bfr = *reinterpret_cast<const s8v*>(Psw + ((size_t)(t * 28 + ks) * 64 + l) * 8);
        acc[i] = __builtin_amdgcn_mfma_f32_16x16x32_bf16(a, bfr, acc[i], 0, 0, 0);
      }
    }
  }
  const int r0 = (l >> 4) * 4;
#pragma unroll
  for (int i = 0; i < 5; ++i) {
    const int t = w + 4 * i;
    if (t < 17) {
#pragma unroll
      for (int r = 0; r < 4; ++r) xl[r0 + r][t * 16 + (l & 15)] = acc[i][r];
    }
  }
  __syncthreads();
  for (int bb = w; bb < 16; bb += 4) {
    const int b = m0 + bb;
    float v[5];
    float sum = 0.f, sq = 0.f;
#pragma unroll
    for (int k = 0; k < 5; ++k) {
      const int o = l + 64 * k;
      v[k] = 0.f;
      if (o < 272) {
        const float r = (o < 172) ? node[(size_t)b * 172 + o] : timef[(size_t)b * 100 + (o - 172)];
        const float x = xl[bb][o] + bO[o] + r;
        v[k] = x;
        sum += x;
        sq = fmaf(x, x, sq);
      }
    }
#pragma unroll
    for (int off = 32; off >= 1; off >>= 1) {
      sum += __shfl_xor(sum, off, 64);
      sq += __shfl_xor(sq, off, 64);
    }
    const float mu = sum * (1.0f / 272.0f);
    const float var = sq * (1.0f / 272.0f) - mu * mu;
    const float rs = rsqrtf(var + kLnEps);
#pragma unroll
    for (int k = 0; k < 5; ++k) {
      const int o = l + 64 * k;
      if (o < 272) out[(size_t)b * 272 + o] = (v[k] - mu) * rs * g[o] + be[o];
    }
  }
}

extern "C" void kernel_launch(void* const* d_in, const int* in_sizes, int n_in,
                              void* d_out, int out_size, void* d_ws, size_t ws_size,
                              hipStream_t stream) {
  const float* node = (const float*)d_in[0];
  const float* timef = (const float*)d_in[1];
  const float* nnode = (const float*)d_in[2];
  const float* ntime = (const float*)d_in[3];
  const float* nedge = (const float*)d_in[4];
  const int* mask = (const int*)d_in[5];
  const float* WQ = (const float*)d_in[6];
  const float* WK = (const float*)d_in[7];
  const float* WV = (const float*)d_in[8];
  const float* WO = (const float*)d_in[9];
  const float* bO = (const float*)d_in[10];
  const float* g = (const float*)d_in[11];
  const float* be = (const float*)d_in[12];

  char* ws = (char*)d_ws;
  unsigned short* Msw = (unsigned short*)(ws + kOffMsw);
  unsigned short* Psw = (unsigned short*)(ws + kOffPsw);
  unsigned short* QT16 = (unsigned short*)(ws + kOffQT16);
  float* out = (float*)d_out;

  hipLaunchKernelGGL(k_build_msw, dim3(56 * 9 * 8), dim3(64), 0, stream, WQ, WK, Msw);
  hipLaunchKernelGGL(k_build_psw, dim3(17 * 28 * 8), dim3(64), 0, stream, WO, WV, Psw);
  hipLaunchKernelGGL(k_gemm_a, dim3(kB / 16), dim3(256), 0, stream, node, timef, Msw, QT16);
  hipLaunchKernelGGL(k_attn, dim3(kB / 4), dim3(256), 0, stream, nnode, nedge, ntime, mask, QT16);
  hipLaunchKernelGGL(k_out_mfma, dim3(kB / 16), dim3(256), 0, stream, QT16, Psw, node, timef, bO, g, be, out);
}